// Round 5
// baseline (148.823 us; speedup 1.0000x reference)
//
#include <hip/hip_runtime.h>
#include <hip/hip_bf16.h>

typedef __bf16 bf16_t;
typedef __attribute__((ext_vector_type(8))) __bf16 bf16x8;
typedef __attribute__((ext_vector_type(4))) float f32x4;

#define SEQ    2048
#define DMODEL 1024
#define DPROJ  256
#define NBATCH 4

__device__ __forceinline__ bf16x8 cvt8(const float4& lo, const float4& hi) {
    bf16x8 v;
    v[0] = (bf16_t)lo.x; v[1] = (bf16_t)lo.y; v[2] = (bf16_t)lo.z; v[3] = (bf16_t)lo.w;
    v[4] = (bf16_t)hi.x; v[5] = (bf16_t)hi.y; v[6] = (bf16_t)hi.z; v[7] = (bf16_t)hi.w;
    return v;
}

// async global->LDS, 16 bytes per lane. LDS dest = wave-uniform base + lane*16.
__device__ __forceinline__ void gl_lds16(const void* g, void* l) {
    __builtin_amdgcn_global_load_lds(
        (const __attribute__((address_space(1))) unsigned int*)g,
        (__attribute__((address_space(3))) unsigned int*)l, 16, 0, 0);
}

// ---------------------------------------------------------------------------
// Kernel 0: one-time W fp32 -> bf16 (1 MB -> 512 KB), so proj's B-frag loads
// are single b128s with no per-step convert.
// ---------------------------------------------------------------------------
__global__ __launch_bounds__(256) void wcvt_kernel(
    const float* __restrict__ W, bf16_t* __restrict__ Wb)
{
    const int idx = (blockIdx.x * 256 + threadIdx.x) * 8;
    float4 lo = *(const float4*)(W + idx);
    float4 hi = *(const float4*)(W + idx + 4);
    *(bf16x8*)(Wb + idx) = cvt8(lo, hi);
}

// ---------------------------------------------------------------------------
// Kernel 1: H[m,p] = relu( sum_d X[m,d]*W[p,d] + bias[p] ), H stored bf16.
// BARRIER-FREE streaming: no LDS. Each lane loads its MFMA fragments
// directly from global (A: row=l16-derived, k=quad*8 -> 2 float4 per frag,
// full 128B-line utilization across quads; B: one b128 from bf16 W).
// Wave = 32x32 outputs (2x2 frags), block 64x64, grid (128,4)=512 blocks
// = 2 blocks/CU. Distance-2 register prefetch; compiler schedules freely
// (no s_barrier -> no vmcnt(0) drain).
// ---------------------------------------------------------------------------
__global__ __launch_bounds__(256) void proj_kernel(
    const float* __restrict__ X, const bf16_t* __restrict__ Wb,
    const float* __restrict__ bias, bf16_t* __restrict__ H)
{
    const int m0 = blockIdx.x * 64;
    const int n0 = blockIdx.y * 64;
    const int tid  = threadIdx.x;
    const int lane = tid & 63;
    const int wave = tid >> 6;
    const int quad = lane >> 4;
    const int l16  = lane & 15;
    const int wm = (wave & 1) * 32;
    const int wn = (wave >> 1) * 32;

    const float*  xrow[2];
    const bf16_t* wrow[2];
    #pragma unroll
    for (int i = 0; i < 2; ++i)
        xrow[i] = X + (size_t)(m0 + wm + i * 16 + l16) * DMODEL + quad * 8;
    #pragma unroll
    for (int j = 0; j < 2; ++j)
        wrow[j] = Wb + (size_t)(n0 + wn + j * 16 + l16) * DMODEL + quad * 8;

    float4 xs[2][2][2];   // [stage][i][half]
    bf16x8 wf[2][2];      // [stage][j]
    #pragma unroll
    for (int s = 0; s < 2; ++s) {
        #pragma unroll
        for (int i = 0; i < 2; ++i) {
            xs[s][i][0] = *(const float4*)(xrow[i] + s * 32);
            xs[s][i][1] = *(const float4*)(xrow[i] + s * 32 + 4);
        }
        #pragma unroll
        for (int j = 0; j < 2; ++j)
            wf[s][j] = *(const bf16x8*)(wrow[j] + s * 32);
    }

    f32x4 acc[2][2] = {};

    for (int kk = 0; kk < 16; ++kk) {
        #pragma unroll
        for (int s = 0; s < 2; ++s) {
            const int step = kk * 2 + s;
            bf16x8 af[2], bfr[2];
            #pragma unroll
            for (int i = 0; i < 2; ++i)
                af[i] = cvt8(xs[s][i][0], xs[s][i][1]);
            #pragma unroll
            for (int j = 0; j < 2; ++j)
                bfr[j] = wf[s][j];

            if (step < 30) {            // prefetch step+2 into this stage
                const int k = (step + 2) * 32;
                #pragma unroll
                for (int i = 0; i < 2; ++i) {
                    xs[s][i][0] = *(const float4*)(xrow[i] + k);
                    xs[s][i][1] = *(const float4*)(xrow[i] + k + 4);
                }
                #pragma unroll
                for (int j = 0; j < 2; ++j)
                    wf[s][j] = *(const bf16x8*)(wrow[j] + k);
            }

            #pragma unroll
            for (int i = 0; i < 2; ++i)
                #pragma unroll
                for (int j = 0; j < 2; ++j)
                    acc[i][j] = __builtin_amdgcn_mfma_f32_16x16x32_bf16(
                        af[i], bfr[j], acc[i][j], 0, 0, 0);
        }
    }

    #pragma unroll
    for (int i = 0; i < 2; ++i) {
        #pragma unroll
        for (int j = 0; j < 2; ++j) {
            const int gn = n0 + wn + j * 16 + l16;
            const float bv = bias[gn];
            #pragma unroll
            for (int r = 0; r < 4; ++r) {
                const int gm = m0 + wm + i * 16 + quad * 4 + r;
                float v = acc[i][j][r] + bv;
                v = v > 0.f ? v : 0.f;
                H[(size_t)gm * DPROJ + gn] = (bf16_t)v;
            }
        }
    }
}

// ---------------------------------------------------------------------------
// Kernel 2: Out[b,i,j] = scale * sum_p H[b,i,p]*H[b,j,p] + off.
// UNCHANGED from R4 (known-good): upper-triangle 128x128 blocks, mirror
// writes; global_load_lds w=16, XOR-swizzled; 512 threads.
// ---------------------------------------------------------------------------
__global__ __launch_bounds__(512) void score_kernel(
    const bf16_t* __restrict__ H, const float* __restrict__ clf_w,
    const float* __restrict__ clf_b, float* __restrict__ Out)
{
    __shared__ __align__(16) bf16_t As[128 * 64];   // 16 KB
    __shared__ __align__(16) bf16_t Bs[128 * 64];   // 16 KB

    int t = blockIdx.x, bi = 0, rl = SEQ / 128;
    while (t >= rl) { t -= rl; --rl; ++bi; }
    const int bj = bi + t;
    const int b  = blockIdx.y;
    const int m0 = bi * 128;
    const int n0 = bj * 128;
    const bf16_t* Hb = H + (size_t)b * SEQ * DPROJ;
    float* Ob = Out + (size_t)b * SEQ * SEQ;

    const int tid  = threadIdx.x;
    const int lane = tid & 63;
    const int wave = tid >> 6;
    const int quad = lane >> 4;
    const int l16  = lane & 15;
    const int wm = (wave & 3) * 32;
    const int wn = (wave >> 2) * 64;
    const int swz = l16 & 7;

    const bf16_t* gA[2];
    const bf16_t* gB[2];
    bf16_t* lA[2];
    bf16_t* lB[2];
    #pragma unroll
    for (int t2 = 0; t2 < 2; ++t2) {
        const int g   = (wave * 2 + t2) * 64 + lane;
        const int row = g >> 3;
        const int gc  = (g & 7) ^ (row & 7);
        gA[t2] = Hb + (size_t)(m0 + row) * DPROJ + gc * 8;
        gB[t2] = Hb + (size_t)(n0 + row) * DPROJ + gc * 8;
        lA[t2] = As + (wave * 2 + t2) * 512;
        lB[t2] = Bs + (wave * 2 + t2) * 512;
    }

    f32x4 acc[2][4] = {};

    for (int kt = 0; kt < 4; ++kt) {
        __syncthreads();
        #pragma unroll
        for (int t2 = 0; t2 < 2; ++t2) {
            gl_lds16(gA[t2], lA[t2]);
            gl_lds16(gB[t2], lB[t2]);
        }
        __syncthreads();
        #pragma unroll
        for (int t2 = 0; t2 < 2; ++t2) { gA[t2] += 64; gB[t2] += 64; }

        #pragma unroll
        for (int ks = 0; ks < 2; ++ks) {
            const int ch = (((ks << 2) | quad) ^ swz) * 8;
            bf16x8 af[2], bfr[4];
            #pragma unroll
            for (int i = 0; i < 2; ++i)
                af[i] = *(const bf16x8*)&As[(wm + i * 16 + l16) * 64 + ch];
            #pragma unroll
            for (int j = 0; j < 4; ++j)
                bfr[j] = *(const bf16x8*)&Bs[(wn + j * 16 + l16) * 64 + ch];
            #pragma unroll
            for (int i = 0; i < 2; ++i)
                #pragma unroll
                for (int j = 0; j < 4; ++j)
                    acc[i][j] = __builtin_amdgcn_mfma_f32_16x16x32_bf16(
                        af[i], bfr[j], acc[i][j], 0, 0, 0);
        }
    }

    const float scale = clf_w[0];
    const float off   = clf_b[0];

    #pragma unroll
    for (int i = 0; i < 2; ++i)
        #pragma unroll
        for (int j = 0; j < 4; ++j)
            #pragma unroll
            for (int r = 0; r < 4; ++r) {
                const int gm = m0 + wm + i * 16 + quad * 4 + r;
                const int gn = n0 + wn + j * 16 + l16;
                Ob[(size_t)gm * SEQ + gn] = acc[i][j][r] * scale + off;
            }

    if (bi != bj) {
        #pragma unroll
        for (int i = 0; i < 2; ++i)
            #pragma unroll
            for (int j = 0; j < 4; ++j) {
                const int gn = n0 + wn + j * 16 + l16;
                const int gm = m0 + wm + i * 16 + quad * 4;
                float4 v;
                v.x = acc[i][j][0] * scale + off;
                v.y = acc[i][j][1] * scale + off;
                v.z = acc[i][j][2] * scale + off;
                v.w = acc[i][j][3] * scale + off;
                *(float4*)&Ob[(size_t)gn * SEQ + gm] = v;
            }
    }
}

extern "C" void kernel_launch(void* const* d_in, const int* in_sizes, int n_in,
                              void* d_out, int out_size, void* d_ws, size_t ws_size,
                              hipStream_t stream) {
    const float* X    = (const float*)d_in[0];  // [4,2048,1024]
    const float* W    = (const float*)d_in[1];  // [256,1024]
    const float* bias = (const float*)d_in[2];  // [256]
    const float* clfw = (const float*)d_in[3];  // [1,1]
    const float* clfb = (const float*)d_in[4];  // [1]
    float* Out = (float*)d_out;                 // [4,2048,2048]
    bf16_t* H  = (bf16_t*)d_ws;                 // [8192,256] bf16 = 4 MB
    bf16_t* Wb = (bf16_t*)d_ws + (size_t)8192 * DPROJ;  // [256,1024] bf16 = 512 KB

    wcvt_kernel<<<DPROJ * DMODEL / (256 * 8), 256, 0, stream>>>(W, Wb);

    dim3 g1(NBATCH * SEQ / 64, DPROJ / 64, 1);  // 128 x 4 = 512 blocks
    proj_kernel<<<g1, 256, 0, stream>>>(X, Wb, bias, H);

    const int ntile = SEQ / 128;                // 16
    dim3 g2(ntile * (ntile + 1) / 2, NBATCH);   // 136 x 4 = 544 blocks
    score_kernel<<<g2, 512, 0, stream>>>(H, clfw, clfb, Out);
}

// Round 6
// 121.270 us; speedup vs baseline: 1.2272x; 1.2272x over previous
//
#include <hip/hip_runtime.h>
#include <hip/hip_bf16.h>

typedef __bf16 bf16_t;
typedef __attribute__((ext_vector_type(8))) __bf16 bf16x8;
typedef __attribute__((ext_vector_type(4))) float f32x4;

#define SEQ    2048
#define DMODEL 1024
#define DPROJ  256
#define NBATCH 4

__device__ __forceinline__ bf16x8 cvt8(const float4& lo, const float4& hi) {
    bf16x8 v;
    v[0] = (bf16_t)lo.x; v[1] = (bf16_t)lo.y; v[2] = (bf16_t)lo.z; v[3] = (bf16_t)lo.w;
    v[4] = (bf16_t)hi.x; v[5] = (bf16_t)hi.y; v[6] = (bf16_t)hi.z; v[7] = (bf16_t)hi.w;
    return v;
}

// async global->LDS, 16 bytes per lane. LDS dest = wave-uniform base + lane*16.
__device__ __forceinline__ void gl_lds16(const void* g, void* l) {
    __builtin_amdgcn_global_load_lds(
        (const __attribute__((address_space(1))) unsigned int*)g,
        (__attribute__((address_space(3))) unsigned int*)l, 16, 0, 0);
}

// ---------------------------------------------------------------------------
// Kernel 1 (R4 known-good, ~23us): H[m,p] = relu(sum_d X[m,d]*W[p,d] + b[p]).
// BM=BN=64, BK=64, grid 512, LDS staging + distance-2 VGPR prefetch.
// ---------------------------------------------------------------------------
__global__ __launch_bounds__(256) void proj_kernel(
    const float* __restrict__ X, const float* __restrict__ W,
    const float* __restrict__ bias, bf16_t* __restrict__ H)
{
    __shared__ __align__(16) bf16_t Xs[64 * 64];
    __shared__ __align__(16) bf16_t Ws[64 * 64];

    const int m0 = blockIdx.x * 64;
    const int n0 = blockIdx.y * 64;
    const int tid  = threadIdx.x;
    const int lane = tid & 63;
    const int wave = tid >> 6;
    const int quad = lane >> 4;
    const int l16  = lane & 15;
    const int wm = (wave & 1) * 32;
    const int wn = (wave >> 1) * 32;
    const int swz = l16 & 7;

    int srow[2], scol[2];
    bf16_t* lx[2];
    bf16_t* lw[2];
    #pragma unroll
    for (int r = 0; r < 2; ++r) {
        const int p = r * 256 + tid;
        srow[r] = p >> 3;
        scol[r] = p & 7;
        const int cs = (scol[r] ^ (srow[r] & 7)) * 8;
        lx[r] = Xs + srow[r] * 64 + cs;
        lw[r] = Ws + srow[r] * 64 + cs;
    }

    float4 xr[2][2][2], wr[2][2][2];   // [stage][r][half]

    #pragma unroll
    for (int s = 0; s < 2; ++s) {
        const int k0 = s * 64;
        #pragma unroll
        for (int r = 0; r < 2; ++r) {
            const float* gx = X + (size_t)(m0 + srow[r]) * DMODEL + k0 + scol[r] * 8;
            xr[s][r][0] = *(const float4*)gx;
            xr[s][r][1] = *(const float4*)(gx + 4);
            const float* gw = W + (size_t)(n0 + srow[r]) * DMODEL + k0 + scol[r] * 8;
            wr[s][r][0] = *(const float4*)gw;
            wr[s][r][1] = *(const float4*)(gw + 4);
        }
    }

    f32x4 acc[2][2] = {};

    #pragma unroll
    for (int kt = 0; kt < 16; ++kt) {
        const int s = kt & 1;
        __syncthreads();
        #pragma unroll
        for (int r = 0; r < 2; ++r) {
            *(bf16x8*)lx[r] = cvt8(xr[s][r][0], xr[s][r][1]);
            *(bf16x8*)lw[r] = cvt8(wr[s][r][0], wr[s][r][1]);
        }
        __syncthreads();

        if (kt < 14) {
            const int k0 = (kt + 2) * 64;
            #pragma unroll
            for (int r = 0; r < 2; ++r) {
                const float* gx = X + (size_t)(m0 + srow[r]) * DMODEL + k0 + scol[r] * 8;
                xr[s][r][0] = *(const float4*)gx;
                xr[s][r][1] = *(const float4*)(gx + 4);
                const float* gw = W + (size_t)(n0 + srow[r]) * DMODEL + k0 + scol[r] * 8;
                wr[s][r][0] = *(const float4*)gw;
                wr[s][r][1] = *(const float4*)(gw + 4);
            }
        }

        #pragma unroll
        for (int ks = 0; ks < 2; ++ks) {
            bf16x8 af[2], bfr[2];
            #pragma unroll
            for (int i = 0; i < 2; ++i) {
                const int ch = (((ks << 2) | quad) ^ swz) * 8;
                af[i]  = *(const bf16x8*)&Xs[(wm + i * 16 + l16) * 64 + ch];
                bfr[i] = *(const bf16x8*)&Ws[(wn + i * 16 + l16) * 64 + ch];
            }
            #pragma unroll
            for (int i = 0; i < 2; ++i)
                #pragma unroll
                for (int j = 0; j < 2; ++j)
                    acc[i][j] = __builtin_amdgcn_mfma_f32_16x16x32_bf16(
                        af[i], bfr[j], acc[i][j], 0, 0, 0);
        }
    }

    #pragma unroll
    for (int i = 0; i < 2; ++i) {
        #pragma unroll
        for (int j = 0; j < 2; ++j) {
            const int gn = n0 + wn + j * 16 + l16;
            const float bv = bias[gn];
            #pragma unroll
            for (int r = 0; r < 4; ++r) {
                const int gm = m0 + wm + i * 16 + quad * 4 + r;
                float v = acc[i][j][r] + bv;
                v = v > 0.f ? v : 0.f;
                H[(size_t)gm * DPROJ + gn] = (bf16_t)v;
            }
        }
    }
}

// ---------------------------------------------------------------------------
// Kernel 2: Out[b,i,j] = scale * sum_p H[b,i,p]*H[b,j,p] + off.
// 64x64 TRIANGULAR tiles: 528/batch, 2112 blocks, 256 thr, 16KB LDS ->
// 8 co-resident blocks/CU (32 waves). Latency hidden by block turnover
// (what the 6.2TB/s fills demonstrate), not per-wave prefetch.
// Each wave = 32x32 quadrant (2x2 frags, 16 acc VGPR). Mirror tile written
// transposed via float4 (acc[i][j] = 4 consecutive rows, one col).
// ---------------------------------------------------------------------------
__global__ __launch_bounds__(256, 8) void score_kernel(
    const bf16_t* __restrict__ H, const float* __restrict__ clf_w,
    const float* __restrict__ clf_b, float* __restrict__ Out)
{
    __shared__ __align__(16) bf16_t As[64 * 64];   // 8 KB
    __shared__ __align__(16) bf16_t Bs[64 * 64];   // 8 KB

    // triangular decode: blockIdx.x in [0,528) -> (bi,bj), bi<=bj, T=32
    int t = blockIdx.x, bi = 0, rl = SEQ / 64;
    while (t >= rl) { t -= rl; --rl; ++bi; }
    const int bj = bi + t;
    const int b  = blockIdx.y;
    const int m0 = bi * 64;
    const int n0 = bj * 64;
    const bf16_t* Hb = H + (size_t)b * SEQ * DPROJ;
    float* Ob = Out + (size_t)b * SEQ * SEQ;

    const int tid  = threadIdx.x;
    const int lane = tid & 63;
    const int wave = tid >> 6;
    const int quad = lane >> 4;
    const int l16  = lane & 15;
    const int wm = (wave & 1) * 32;
    const int wn = (wave >> 1) * 32;
    const int swz = l16 & 7;

    // staging: 512 16B chunks per matrix per K-tile; instr t2 in {0,1}:
    // g = (wave*2+t2)*64 + lane; row = g>>3, stored chunk = (g&7)^(row&7)
    const bf16_t* gA[2];
    const bf16_t* gB[2];
    bf16_t* lA[2];
    bf16_t* lB[2];
    #pragma unroll
    for (int t2 = 0; t2 < 2; ++t2) {
        const int g   = (wave * 2 + t2) * 64 + lane;
        const int row = g >> 3;
        const int gc  = (g & 7) ^ (row & 7);
        gA[t2] = Hb + (size_t)(m0 + row) * DPROJ + gc * 8;
        gB[t2] = Hb + (size_t)(n0 + row) * DPROJ + gc * 8;
        lA[t2] = As + (wave * 2 + t2) * 512;
        lB[t2] = Bs + (wave * 2 + t2) * 512;
    }

    f32x4 acc[2][2] = {};

    for (int kt = 0; kt < 4; ++kt) {
        __syncthreads();
        #pragma unroll
        for (int t2 = 0; t2 < 2; ++t2) {
            gl_lds16(gA[t2], lA[t2]);
            gl_lds16(gB[t2], lB[t2]);
        }
        __syncthreads();               // drains vmcnt -> data visible
        #pragma unroll
        for (int t2 = 0; t2 < 2; ++t2) { gA[t2] += 64; gB[t2] += 64; }

        #pragma unroll
        for (int ks = 0; ks < 2; ++ks) {
            const int ch = (((ks << 2) | quad) ^ swz) * 8;
            bf16x8 af[2], bfr[2];
            #pragma unroll
            for (int i = 0; i < 2; ++i) {
                af[i]  = *(const bf16x8*)&As[(wm + i * 16 + l16) * 64 + ch];
                bfr[i] = *(const bf16x8*)&Bs[(wn + i * 16 + l16) * 64 + ch];
            }
            #pragma unroll
            for (int i = 0; i < 2; ++i)
                #pragma unroll
                for (int j = 0; j < 2; ++j)
                    acc[i][j] = __builtin_amdgcn_mfma_f32_16x16x32_bf16(
                        af[i], bfr[j], acc[i][j], 0, 0, 0);
        }
    }

    const float scale = clf_w[0];
    const float off   = clf_b[0];

    // direct tile (bi,bj)
    #pragma unroll
    for (int i = 0; i < 2; ++i)
        #pragma unroll
        for (int j = 0; j < 2; ++j)
            #pragma unroll
            for (int r = 0; r < 4; ++r) {
                const int gm = m0 + wm + i * 16 + quad * 4 + r;
                const int gn = n0 + wn + j * 16 + l16;
                Ob[(size_t)gm * SEQ + gn] = acc[i][j][r] * scale + off;
            }

    // mirror tile (bj,bi): row gn, 4 consecutive cols gm -> float4 store
    if (bi != bj) {
        #pragma unroll
        for (int i = 0; i < 2; ++i)
            #pragma unroll
            for (int j = 0; j < 2; ++j) {
                const int gn = n0 + wn + j * 16 + l16;
                const int gm = m0 + wm + i * 16 + quad * 4;
                float4 v;
                v.x = acc[i][j][0] * scale + off;
                v.y = acc[i][j][1] * scale + off;
                v.z = acc[i][j][2] * scale + off;
                v.w = acc[i][j][3] * scale + off;
                *(float4*)&Ob[(size_t)gn * SEQ + gm] = v;
            }
    }
}

extern "C" void kernel_launch(void* const* d_in, const int* in_sizes, int n_in,
                              void* d_out, int out_size, void* d_ws, size_t ws_size,
                              hipStream_t stream) {
    const float* X    = (const float*)d_in[0];  // [4,2048,1024]
    const float* W    = (const float*)d_in[1];  // [256,1024]
    const float* bias = (const float*)d_in[2];  // [256]
    const float* clfw = (const float*)d_in[3];  // [1,1]
    const float* clfb = (const float*)d_in[4];  // [1]
    float* Out = (float*)d_out;                 // [4,2048,2048]
    bf16_t* H  = (bf16_t*)d_ws;                 // [8192,256] bf16 = 4 MB

    dim3 g1(NBATCH * SEQ / 64, DPROJ / 64, 1);  // 128 x 4 = 512 blocks
    proj_kernel<<<g1, 256, 0, stream>>>(X, W, bias, H);

    const int ntile = SEQ / 64;                 // 32
    dim3 g2(ntile * (ntile + 1) / 2, NBATCH);   // 528 x 4 = 2112 blocks
    score_kernel<<<g2, 256, 0, stream>>>(H, clfw, clfb, Out);
}